// Round 1
// baseline (1078.401 us; speedup 1.0000x reference)
//
#include <hip/hip_runtime.h>

#define Bc 8
#define Td 4096
#define Hd 1024
#define N3 3072
#define Md (Bc*Td)      // 32768
#define Kd Hd           // 1024

#define NC 64           // chunks along T
#define CL (Td/NC)      // 64 steps per chunk

// 256^2 deep-pipelined GEMM geometry
#define BM2 256
#define BN2 256
#define BK2 64
#define NT (Kd/BK2)     // 16 K-tiles

typedef _Float16 half8 __attribute__((ext_vector_type(8)));
typedef _Float16 half4v __attribute__((ext_vector_type(4)));
typedef float floatx4 __attribute__((ext_vector_type(4)));

typedef __attribute__((address_space(3))) unsigned int lds_u32;
typedef __attribute__((address_space(1))) const unsigned int glob_u32;

__device__ __forceinline__ void async_lds16(const void* g, void* l) {
    __builtin_amdgcn_global_load_lds((glob_u32*)g, (lds_u32*)l, 16, 0, 0);
}

// sigmoid, single exp+rcp, no overflow
__device__ __forceinline__ float sigm(float x) {
    return 1.0f / (1.0f + __expf(-x));
}
// g(x) = x>=0 ? x+0.5 : sigmoid(x); exp(-|x|) never overflows
__device__ __forceinline__ float gfun(float x) {
    float e = __expf(-fabsf(x));
    return (x >= 0.0f) ? (x + 0.5f) : e / (1.0f + e);
}

// ---------------- fp32 -> fp16 convert (vectorized x4) ----------------
__global__ void cvt16(const float4* __restrict__ x, half4v* __restrict__ y, int n4) {
    int i = blockIdx.x * blockDim.x + threadIdx.x;
    if (i < n4) {
        float4 v = x[i];
        half4v o;
        o[0] = (_Float16)v.x; o[1] = (_Float16)v.y;
        o[2] = (_Float16)v.z; o[3] = (_Float16)v.w;
        y[i] = o;
    }
}

// ---------------- W [K,N] fp32 -> Wt [N,K] fp16 (LDS-tiled transpose) --
__global__ void wtrans(const float* __restrict__ W, _Float16* __restrict__ Wt) {
    __shared__ float t[32][33];
    int n0 = blockIdx.x * 32, k0 = blockIdx.y * 32;
    int tx = threadIdx.x, ty = threadIdx.y;
    t[ty][tx] = W[(size_t)(k0 + ty) * N3 + n0 + tx];
    __syncthreads();
    Wt[(size_t)(n0 + ty) * Kd + k0 + tx] = (_Float16)t[tx][ty];
}

// ---------------- GEMM: C[M,N] = A[M,K] * Bt[N,K]^T, fp16 in, fp16 out -
// 256x256 tile, BK=64, 8 waves (2Mx4N), double-buffered 128 KiB LDS.
// Deep pipeline: stage tile t+2 at the tile-t boundary, s_waitcnt vmcnt(8)
// (counted, never 0 in the loop) + raw s_barrier. 4 compute phases per
// K-tile, each {ds_read quadrant; barrier; setprio(1); 16 MFMA; setprio(0);
// barrier}. XOR chunk-swizzle on LDS rows (verified conflict-free).
// XCD-aware block swizzle (nwg=1536 % 8 == 0 -> simple bijective form).
__global__ __launch_bounds__(512, 2) void gemm_f16_bt_256(
    const _Float16* __restrict__ A,   // [M,K]
    const _Float16* __restrict__ Bt,  // [N,K]
    _Float16* __restrict__ C)         // [M,N]
{
    __shared__ _Float16 As[2][BM2 * BK2];   // 2 x 32 KiB
    __shared__ _Float16 Bs[2][BN2 * BK2];   // 2 x 32 KiB

    const int tid  = threadIdx.x;
    const int wave = tid >> 6;        // 0..7
    const int lane = tid & 63;

    // XCD swizzle: 1536 blocks, 8 XCDs, 192 blocks/XCD chunk.
    const int bid = blockIdx.x;
    const int swz = (bid & 7) * (1536 / 8) + (bid >> 3);
    const int by  = swz / 12;         // M-tile index 0..127
    const int bx  = swz - by * 12;    // N-tile index 0..11
    const int bm  = by * BM2;
    const int bn  = bx * BN2;

    const int wm   = (wave >> 2) * 128;   // 0 or 128
    const int wn   = (wave & 3) * 64;     // 0,64,128,192
    const int quad = lane >> 4;
    const int lr   = lane & 15;

    floatx4 acc[8][4];
#pragma unroll
    for (int i = 0; i < 8; ++i)
#pragma unroll
        for (int j = 0; j < 4; ++j) { floatx4 z = {0.f,0.f,0.f,0.f}; acc[i][j] = z; }

    // ---- staging: 4 loads per operand per K-tile per thread (16B each).
    // Issue r covers rows r*64 + wave*8 .. +7; lane l -> row +(l>>3), chunk l&7.
    // LDS is linear; source chunk pre-swizzled: kc = (l&7) ^ (row&7).
    auto stageA = [&](int sel, int kt) {
        const int k0 = kt * BK2;
#pragma unroll
        for (int r = 0; r < 4; ++r) {
            int m  = r * 64 + wave * 8 + (lane >> 3);
            int kc = ((lane & 7) ^ (m & 7)) << 3;
            const _Float16* ga = A + (size_t)(bm + m) * Kd + (k0 + kc);
            char* la = (char*)&As[sel][0] + (r * 64 + wave * 8) * 128;
            async_lds16(ga, la);
        }
    };
    auto stageB = [&](int sel, int kt) {
        const int k0 = kt * BK2;
#pragma unroll
        for (int r = 0; r < 4; ++r) {
            int m  = r * 64 + wave * 8 + (lane >> 3);
            int kc = ((lane & 7) ^ (m & 7)) << 3;
            const _Float16* gb = Bt + (size_t)(bn + m) * Kd + (k0 + kc);
            char* lb = (char*)&Bs[sel][0] + (r * 64 + wave * 8) * 128;
            async_lds16(gb, lb);
        }
    };

    // ---- fragment reads (XOR-deswizzled), 2 k-slices per fragment row
    auto dsA = [&](int sel, int ihalf, half8 (&af)[4][2]) {
#pragma unroll
        for (int i = 0; i < 4; ++i) {
            int row = wm + (ihalf * 4 + i) * 16 + lr;
#pragma unroll
            for (int ks = 0; ks < 2; ++ks) {
                int ck = ((ks * 4 + quad) ^ (row & 7)) << 3;
                af[i][ks] = *(const half8*)&As[sel][row * BK2 + ck];
            }
        }
    };
    auto dsB = [&](int sel, int jhalf, half8 (&bf)[2][2]) {
#pragma unroll
        for (int j = 0; j < 2; ++j) {
            int row = wn + (jhalf * 2 + j) * 16 + lr;
#pragma unroll
            for (int ks = 0; ks < 2; ++ks) {
                int ck = ((ks * 4 + quad) ^ (row & 7)) << 3;
                bf[j][ks] = *(const half8*)&Bs[sel][row * BK2 + ck];
            }
        }
    };
    auto mmac = [&](int ihalf, int jhalf, half8 (&af)[4][2], half8 (&bf)[2][2]) {
        __builtin_amdgcn_s_setprio(1);
#pragma unroll
        for (int i = 0; i < 4; ++i)
#pragma unroll
            for (int j = 0; j < 2; ++j)
#pragma unroll
                for (int ks = 0; ks < 2; ++ks)
                    acc[ihalf * 4 + i][jhalf * 2 + j] =
                        __builtin_amdgcn_mfma_f32_16x16x32_f16(
                            af[i][ks], bf[j][ks],
                            acc[ihalf * 4 + i][jhalf * 2 + j], 0, 0, 0);
        __builtin_amdgcn_s_setprio(0);
    };

    // 4 phases per K-tile: (i-lo,j-lo) (i-lo,j-hi) (i-hi,j-lo) (i-hi,j-hi)
    auto compute_tile = [&](int sel) {
        half8 af[4][2];
        half8 bflo[2][2], bfhi[2][2];
        // P0
        dsA(sel, 0, af); dsB(sel, 0, bflo);
        __builtin_amdgcn_s_barrier();
        mmac(0, 0, af, bflo);
        __builtin_amdgcn_s_barrier();
        // P1
        dsB(sel, 1, bfhi);
        __builtin_amdgcn_s_barrier();
        mmac(0, 1, af, bfhi);
        __builtin_amdgcn_s_barrier();
        // P2
        dsA(sel, 1, af);
        __builtin_amdgcn_s_barrier();
        mmac(1, 0, af, bflo);
        __builtin_amdgcn_s_barrier();
        // P3 (register-only)
        mmac(1, 1, af, bfhi);
    };

    // ---- pipeline ----
    stageA(0, 0); stageB(0, 0);
    stageA(1, 1); stageB(1, 1);
    asm volatile("s_waitcnt vmcnt(8)" ::: "memory");   // tile0 landed, tile1 in flight
    __builtin_amdgcn_s_barrier();

    for (int t = 0; t < NT - 2; ++t) {                 // t = 0..13
        const int sel = t & 1;
        compute_tile(sel);
        // buf[sel] fully consumed (all reads lgkm-waited before last barrier)
        stageA(sel, t + 2); stageB(sel, t + 2);
        asm volatile("s_waitcnt vmcnt(8)" ::: "memory"); // tile t+1 landed, t+2 in flight
        __builtin_amdgcn_s_barrier();
    }
    compute_tile(0);                                   // tile 14
    asm volatile("s_waitcnt vmcnt(0)" ::: "memory");   // tile 15 landed
    __builtin_amdgcn_s_barrier();
    compute_tile(1);                                   // tile 15

    // epilogue: C/D layout col = lane&15, row = quad*4 + reg  [m89-verified]
#pragma unroll
    for (int i = 0; i < 8; ++i) {
#pragma unroll
        for (int j = 0; j < 4; ++j) {
            int row0 = bm + wm + i * 16 + quad * 4;
            int col  = bn + wn + j * 16 + lr;
#pragma unroll
            for (int r = 0; r < 4; ++r)
                C[(size_t)(row0 + r) * N3 + col] = (_Float16)acc[i][j][r];
        }
    }
}

// ---------------- scan phase 1: per-chunk (A, B) composition ----------
// 4 channels/thread: half4 (8B) loads, 4 independent chains for ILP.
__global__ __launch_bounds__(256) void scan_phase1(
    const _Float16* __restrict__ Z, float* __restrict__ cA, float* __restrict__ cB)
{
    int ch = threadIdx.x * 4;                  // gridDim.x == 1, covers H=1024
    int c  = blockIdx.y;
    int b  = blockIdx.z;
    const _Float16* zp = Z + ((size_t)(b * Td + c * CL)) * N3 + ch;
    float Ap[4] = {1.f, 1.f, 1.f, 1.f};
    float Bv[4] = {0.f, 0.f, 0.f, 0.f};
#pragma unroll 4
    for (int t = 0; t < CL; ++t) {
        half4v h4 = *(const half4v*)(zp);
        half4v g4 = *(const half4v*)(zp + Hd);
#pragma unroll
        for (int i = 0; i < 4; ++i) {
            float sg = sigm((float)g4[i]);
            float at = 1.0f - sg;
            float bt = sg * gfun((float)h4[i]);
            Ap[i] *= at;
            Bv[i] = fmaf(at, Bv[i], bt);
        }
        zp += N3;
    }
    size_t o = ((size_t)b * NC + c) * Hd + ch;
    *(float4*)&cA[o] = make_float4(Ap[0], Ap[1], Ap[2], Ap[3]);
    *(float4*)&cB[o] = make_float4(Bv[0], Bv[1], Bv[2], Bv[3]);
}

// ---------------- scan phase 2: prefix over chunks (float4) -----------
__global__ void scan_phase2(const float* __restrict__ cA, const float* __restrict__ cB,
                            float* __restrict__ cS)
{
    int u = (blockIdx.x * 256 + threadIdx.x) * 4;   // B*H/4 = 2048 threads
    int b = u >> 10, ch = u & 1023;
    float4 s = make_float4(0.f, 0.f, 0.f, 0.f);
    for (int c = 0; c < NC; ++c) {
        size_t o = ((size_t)b * NC + c) * Hd + ch;
        *(float4*)&cS[o] = s;
        float4 a = *(const float4*)&cA[o];
        float4 v = *(const float4*)&cB[o];
        s.x = fmaf(a.x, s.x, v.x);
        s.y = fmaf(a.y, s.y, v.y);
        s.z = fmaf(a.z, s.z, v.z);
        s.w = fmaf(a.w, s.w, v.w);
    }
}

// ---------------- scan phase 3: rescan + highway gate -----------------
// 4 channels/thread. hin32/hin16: exactly one non-null; same for hout.
__global__ __launch_bounds__(256) void scan_phase3(
    const _Float16* __restrict__ Z, const float* __restrict__ cS,
    const float* __restrict__ hin32, const _Float16* __restrict__ hin16,
    float* __restrict__ hout32, _Float16* __restrict__ hout16)
{
    int ch = threadIdx.x * 4;                  // gridDim.x == 1
    int c  = blockIdx.y;
    int b  = blockIdx.z;
    float s[4];
    {
        float4 s4 = *(const float4*)&cS[((size_t)b * NC + c) * Hd + ch];
        s[0] = s4.x; s[1] = s4.y; s[2] = s4.z; s[3] = s4.w;
    }
    const _Float16* zp = Z + ((size_t)(b * Td + c * CL)) * N3 + ch;
    size_t ho = ((size_t)(b * Td + c * CL)) * Hd + ch;
#pragma unroll 2
    for (int t = 0; t < CL; ++t) {
        half4v h4 = *(const half4v*)(zp);
        half4v g4 = *(const half4v*)(zp + Hd);
        half4v p4 = *(const half4v*)(zp + 2 * Hd);
        float hi[4];
        if (hin32) {
            float4 v = *(const float4*)&hin32[ho];
            hi[0] = v.x; hi[1] = v.y; hi[2] = v.z; hi[3] = v.w;
        } else {
            half4v v = *(const half4v*)&hin16[ho];
#pragma unroll
            for (int i = 0; i < 4; ++i) hi[i] = (float)v[i];
        }
        float o[4];
#pragma unroll
        for (int i = 0; i < 4; ++i) {
            float sg = sigm((float)g4[i]);
            float at = 1.0f - sg;
            s[i] = fmaf(at, s[i], sg * gfun((float)h4[i]));
            float gg = sigm((float)p4[i]);
            o[i] = fmaf(gg, s[i] - hi[i], hi[i]);
        }
        if (hout32) *(float4*)&hout32[ho] = make_float4(o[0], o[1], o[2], o[3]);
        if (hout16) {
            half4v v;
#pragma unroll
            for (int i = 0; i < 4; ++i) v[i] = (_Float16)o[i];
            *(half4v*)&hout16[ho] = v;
        }
        zp += N3; ho += Hd;
    }
}

extern "C" void kernel_launch(void* const* d_in, const int* in_sizes, int n_in,
                              void* d_out, int out_size, void* d_ws, size_t ws_size,
                              hipStream_t stream) {
    const float* h  = (const float*)d_in[0];
    const float* W0 = (const float*)d_in[1];
    const float* W1 = (const float*)d_in[2];
    float* out = (float*)d_out;

    char* ws = (char*)d_ws;
    _Float16* Z    = (_Float16*)ws; ws += (size_t)Md * N3 * 2;     // 192 MiB
    _Float16* Hbf  = (_Float16*)ws; ws += (size_t)Md * Kd * 2;     // 64 MiB
    _Float16* Wt   = (_Float16*)ws; ws += (size_t)N3 * Kd * 2;     // 6 MiB
    float* cA   = (float*)ws; ws += (size_t)Bc * NC * Hd * 4;      // 2 MiB
    float* cB   = (float*)ws; ws += (size_t)Bc * NC * Hd * 4;
    float* cS   = (float*)ws; ws += (size_t)Bc * NC * Hd * 4;

    // initial h -> fp16
    {
        int n4 = Md * Kd / 4;
        cvt16<<<n4 / 256, 256, 0, stream>>>((const float4*)h, (half4v*)Hbf, n4);
    }

    for (int l = 0; l < 2; ++l) {
        const float* W = l ? W1 : W0;

        wtrans<<<dim3(N3 / 32, Kd / 32), dim3(32, 32), 0, stream>>>(W, Wt);
        gemm_f16_bt_256<<<dim3((Md / BM2) * (N3 / BN2)), 512, 0, stream>>>(Hbf, Wt, Z);
        scan_phase1<<<dim3(1, NC, Bc), 256, 0, stream>>>(Z, cA, cB);
        scan_phase2<<<(Bc * Hd / 4) / 256, 256, 0, stream>>>(cA, cB, cS);
        if (l == 0) {
            scan_phase3<<<dim3(1, NC, Bc), 256, 0, stream>>>(
                Z, cS, h, nullptr, nullptr, Hbf);
        } else {
            scan_phase3<<<dim3(1, NC, Bc), 256, 0, stream>>>(
                Z, cS, nullptr, Hbf, out, nullptr);
        }
    }
}

// Round 5
// 922.282 us; speedup vs baseline: 1.1693x; 1.1693x over previous
//
#include <hip/hip_runtime.h>

#define Bc 8
#define Td 4096
#define Hd 1024
#define N3 3072
#define Md (Bc*Td)      // 32768
#define Kd Hd           // 1024

#define NC 128          // chunks along T
#define CL (Td/NC)      // 32 steps per chunk

// 256^2 deep-pipelined GEMM geometry
#define BM2 256
#define BN2 256
#define BK2 64
#define NT (Kd/BK2)     // 16 K-tiles
#define NSEG (4*NT)     // 64 staging segments

typedef _Float16 half8 __attribute__((ext_vector_type(8)));
typedef _Float16 half4v __attribute__((ext_vector_type(4)));
typedef float floatx4 __attribute__((ext_vector_type(4)));

typedef __attribute__((address_space(3))) unsigned int lds_u32;
typedef __attribute__((address_space(1))) const unsigned int glob_u32;

__device__ __forceinline__ void async_lds16(const void* g, void* l) {
    __builtin_amdgcn_global_load_lds((glob_u32*)g, (lds_u32*)l, 16, 0, 0);
}

// sigmoid, single exp+rcp, no overflow
__device__ __forceinline__ float sigm(float x) {
    return 1.0f / (1.0f + __expf(-x));
}
// g(x) = x>=0 ? x+0.5 : sigmoid(x); exp(-|x|) never overflows
__device__ __forceinline__ float gfun(float x) {
    float e = __expf(-fabsf(x));
    return (x >= 0.0f) ? (x + 0.5f) : e / (1.0f + e);
}

// ---------------- fp32 -> fp16 convert (vectorized x4) ----------------
__global__ void cvt16(const float4* __restrict__ x, half4v* __restrict__ y, int n4) {
    int i = blockIdx.x * blockDim.x + threadIdx.x;
    if (i < n4) {
        float4 v = x[i];
        half4v o;
        o[0] = (_Float16)v.x; o[1] = (_Float16)v.y;
        o[2] = (_Float16)v.z; o[3] = (_Float16)v.w;
        y[i] = o;
    }
}

// ---------------- W [K,N] fp32 -> Wt [N,K] fp16 (LDS-tiled transpose) --
__global__ void wtrans(const float* __restrict__ W, _Float16* __restrict__ Wt) {
    __shared__ float t[32][33];
    int n0 = blockIdx.x * 32, k0 = blockIdx.y * 32;
    int tx = threadIdx.x, ty = threadIdx.y;
    t[ty][tx] = W[(size_t)(k0 + ty) * N3 + n0 + tx];
    __syncthreads();
    Wt[(size_t)(n0 + ty) * Kd + k0 + tx] = (_Float16)t[tx][ty];
}

// ---------------- GEMM: C[M,N] = A[M,K] * Bt[N,K]^T, fp16 in, fp16 out -
// 256x256 tile, BK=64, 8 waves (2Mx4N), 128 KiB LDS as 8 slots of 16 KiB
// ([sel][slot]: 0=Alo,1=Blo,2=Bhi,3=Ahi; 128 rows x 64 cols each).
// m201-style fine interleave: each of the 4 compute phases per K-tile
// stages ONE half-tile segment (2 global_load_lds/thread), prefetch
// distance 6 segments; counted s_waitcnt vmcnt(4) once per tile (never 0
// in steady state).
//
// R4 POST-MORTEM: R2/R4 both failed with IDENTICAL absmax 3.6015625 ->
// deterministic layout bug, not a race. Found: `bro = wn & 63` masked the
// B-slot local row base to {0,0,0,0}; slots cover 128 rows so the base is
// wn mod 128 = {0,64,0,64}. Fixed to `wn & 127`. (R1 passed because its
// monolithic 256-row Bs tile used wn directly.)
//
// WAR ledger (why slot overwrites are safe): seg s overwrites seg s-8's
// region; stage of seg s issues at phase s-6, >= 1 phase after seg s-8's
// last ds_read phase (A: s-7/s-9; B: s-7/s-9). Each wave's ds_reads
// complete before its phase-closing barrier via (1) rule-18
// sched_barrier(0) pinning each MFMA cluster + its lgkm waits between
// the phase barriers, and (2) explicit s_waitcnt lgkmcnt(0) before every
// closing barrier (≈free). RAW: per-tile vmcnt(4) leaves exactly segs
// 4kt+8,9 outstanding -> tile kt+1 fully landed; barrier makes it
// block-wide.
//
// Raw asm s_barrier (memory clobber) so no compiler vmcnt(0) drain.
// XOR chunk-swizzle on LDS rows (verified conflict-free, R1 counters=0).
// XCD-aware block swizzle (nwg=1536 % 8 == 0 -> simple bijective form).
__global__ __launch_bounds__(512, 2) void gemm_f16_bt_256(
    const _Float16* __restrict__ A,   // [M,K]
    const _Float16* __restrict__ Bt,  // [N,K]
    _Float16* __restrict__ C)         // [M,N]
{
    __shared__ _Float16 lds[2][4][128 * 64];   // 131072 B

    const int tid  = threadIdx.x;
    const int wave = tid >> 6;        // 0..7
    const int lane = tid & 63;

    // XCD swizzle: 1536 blocks, 8 XCDs, 192 blocks/XCD chunk.
    const int bid = blockIdx.x;
    const int swz = (bid & 7) * (1536 / 8) + (bid >> 3);
    const int by  = swz / 12;         // M-tile index 0..127
    const int bx  = swz - by * 12;    // N-tile index 0..11
    const int bm  = by * BM2;
    const int bn  = bx * BN2;

    const int wm   = (wave >> 2) * 128;   // 0 or 128
    const int wn   = (wave & 3) * 64;     // 0,64,128,192
    const int quad = lane >> 4;
    const int lr   = lane & 15;
    const int aslot = wm ? 3 : 0;             // this wave's A half-slot
    const int bslot = (wn >= 128) ? 2 : 1;    // this wave's B half-slot
    const int bro   = wn & 127;               // local row base in B slot (R4 fix)

    floatx4 acc[8][4];
#pragma unroll
    for (int i = 0; i < 8; ++i)
#pragma unroll
        for (int j = 0; j < 4; ++j) { floatx4 z = {0.f,0.f,0.f,0.f}; acc[i][j] = z; }

    // stage one 128x64 segment: seg = 4*ktile + b, b: 0=Blo 1=Alo 2=Bhi 3=Ahi
    auto stage_seg = [&](int seg) {
        const int tt    = seg >> 2;
        const int b     = seg & 3;
        const int sel   = tt & 1;
        const int k0    = tt * BK2;
        const bool isA  = (b & 1);
        const int rbase = (b >= 2) ? 128 : 0;
        const int slot  = (b < 2) ? (1 - b) : b;
        const _Float16* src = isA ? A : Bt;
        const int g0    = (isA ? bm : bn) + rbase;
#pragma unroll
        for (int r = 0; r < 2; ++r) {
            int rl = r * 64 + wave * 8 + (lane >> 3);       // local row 0..127
            int kc = ((lane & 7) ^ (rl & 7)) << 3;          // pre-swizzled source
            const _Float16* g = src + (size_t)(g0 + rl) * Kd + (k0 + kc);
            char* l = (char*)&lds[sel][slot][0] + (r * 64 + wave * 8) * 128;
            async_lds16(g, l);
        }
    };

    // fragment reads (XOR-deswizzled); rows are slot-local (0..127)
    auto dsA = [&](int sel, int ih, half8 (&af)[4][2]) {
#pragma unroll
        for (int i = 0; i < 4; ++i) {
            int row = (ih * 4 + i) * 16 + lr;
#pragma unroll
            for (int ks = 0; ks < 2; ++ks) {
                int ck = ((ks * 4 + quad) ^ (row & 7)) << 3;
                af[i][ks] = *(const half8*)&lds[sel][aslot][row * 64 + ck];
            }
        }
    };
    auto dsB = [&](int sel, int jh, half8 (&bf)[2][2]) {
#pragma unroll
        for (int j = 0; j < 2; ++j) {
            int row = bro + (jh * 2 + j) * 16 + lr;
#pragma unroll
            for (int ks = 0; ks < 2; ++ks) {
                int ck = ((ks * 4 + quad) ^ (row & 7)) << 3;
                bf[j][ks] = *(const half8*)&lds[sel][bslot][row * 64 + ck];
            }
        }
    };
    // sched_barrier(0) fences pin the MFMA cluster (and its lgkmcnt wait)
    // strictly between the enclosing s_barriers (rule #18).
    auto mmac = [&](int ih, int jh, half8 (&af)[4][2], half8 (&bf)[2][2]) {
        __builtin_amdgcn_sched_barrier(0);
        __builtin_amdgcn_s_setprio(1);
#pragma unroll
        for (int i = 0; i < 4; ++i)
#pragma unroll
            for (int j = 0; j < 2; ++j)
#pragma unroll
                for (int ks = 0; ks < 2; ++ks)
                    acc[ih * 4 + i][jh * 2 + j] =
                        __builtin_amdgcn_mfma_f32_16x16x32_f16(
                            af[i][ks], bf[j][ks],
                            acc[ih * 4 + i][jh * 2 + j], 0, 0, 0);
        __builtin_amdgcn_s_setprio(0);
        __builtin_amdgcn_sched_barrier(0);
    };

    half8 af[4][2], bf0[2][2], bf1[2][2];

    // ---- prologue: segments 0..5 (tile0 complete + tile1 Blo,Alo) ----
    for (int s = 0; s < 6; ++s) stage_seg(s);
    asm volatile("s_waitcnt vmcnt(4)" ::: "memory");   // tile0 landed, 2 segs in flight
    asm volatile("s_barrier" ::: "memory");

    for (int kt = 0; kt < NT; ++kt) {
        const int sel = kt & 1;
        const int p = kt * 4;
        // P0: quadrant (0,0); stage seg p+6
        dsA(sel, 0, af); dsB(sel, 0, bf0);
        if (p + 6 < NSEG) stage_seg(p + 6);
        asm volatile("s_barrier" ::: "memory");
        mmac(0, 0, af, bf0);
        asm volatile("s_waitcnt lgkmcnt(0)" ::: "memory");  // reads done pre-barrier
        asm volatile("s_barrier" ::: "memory");
        // P1: quadrant (0,1); stage seg p+7
        dsB(sel, 1, bf1);
        if (p + 7 < NSEG) stage_seg(p + 7);
        asm volatile("s_barrier" ::: "memory");
        mmac(0, 1, af, bf1);
        asm volatile("s_waitcnt lgkmcnt(0)" ::: "memory");
        asm volatile("s_barrier" ::: "memory");
        // P2: quadrant (1,0); stage seg p+8
        dsA(sel, 1, af);
        if (p + 8 < NSEG) stage_seg(p + 8);
        asm volatile("s_barrier" ::: "memory");
        mmac(1, 0, af, bf0);
        asm volatile("s_waitcnt lgkmcnt(0)" ::: "memory");
        asm volatile("s_barrier" ::: "memory");
        // P3: quadrant (1,1), register-only; stage seg p+9
        if (p + 9 < NSEG) stage_seg(p + 9);
        mmac(1, 1, af, bf1);
        if (kt < NT - 2) {
            asm volatile("s_waitcnt vmcnt(4)" ::: "memory");  // next tile landed
            asm volatile("s_barrier" ::: "memory");
        } else if (kt == NT - 2) {
            asm volatile("s_waitcnt vmcnt(0)" ::: "memory");  // last tile landed
            asm volatile("s_barrier" ::: "memory");
        }
    }

    // epilogue: C/D layout col = lane&15, row = quad*4 + reg  [m89-verified]
#pragma unroll
    for (int i = 0; i < 8; ++i) {
#pragma unroll
        for (int j = 0; j < 4; ++j) {
            int row0 = bm + wm + i * 16 + quad * 4;
            int col  = bn + wn + j * 16 + lr;
#pragma unroll
            for (int r = 0; r < 4; ++r)
                C[(size_t)(row0 + r) * N3 + col] = (_Float16)acc[i][j][r];
        }
    }
}

// ---------------- scan phase 1: per-chunk (A, B) composition ----------
// 4 channels/thread: half4 (8B) loads, 4 independent chains for ILP.
__global__ __launch_bounds__(256) void scan_phase1(
    const _Float16* __restrict__ Z, float* __restrict__ cA, float* __restrict__ cB)
{
    int ch = threadIdx.x * 4;                  // gridDim.x == 1, covers H=1024
    int c  = blockIdx.y;
    int b  = blockIdx.z;
    const _Float16* zp = Z + ((size_t)(b * Td + c * CL)) * N3 + ch;
    float Ap[4] = {1.f, 1.f, 1.f, 1.f};
    float Bv[4] = {0.f, 0.f, 0.f, 0.f};
#pragma unroll 4
    for (int t = 0; t < CL; ++t) {
        half4v h4 = *(const half4v*)(zp);
        half4v g4 = *(const half4v*)(zp + Hd);
#pragma unroll
        for (int i = 0; i < 4; ++i) {
            float sg = sigm((float)g4[i]);
            float at = 1.0f - sg;
            float bt = sg * gfun((float)h4[i]);
            Ap[i] *= at;
            Bv[i] = fmaf(at, Bv[i], bt);
        }
        zp += N3;
    }
    size_t o = ((size_t)b * NC + c) * Hd + ch;
    *(float4*)&cA[o] = make_float4(Ap[0], Ap[1], Ap[2], Ap[3]);
    *(float4*)&cB[o] = make_float4(Bv[0], Bv[1], Bv[2], Bv[3]);
}

// ---------------- scan phase 2: prefix over chunks, in-place into cB --
__global__ void scan_phase2(const float* __restrict__ cA, float* __restrict__ cB)
{
    int u = (blockIdx.x * 256 + threadIdx.x) * 4;   // B*H/4 = 2048 threads
    int b = u >> 10, ch = u & 1023;
    float4 s = make_float4(0.f, 0.f, 0.f, 0.f);
    for (int c = 0; c < NC; ++c) {
        size_t o = ((size_t)b * NC + c) * Hd + ch;
        float4 a = *(const float4*)&cA[o];
        float4 v = *(const float4*)&cB[o];
        *(float4*)&cB[o] = s;                       // exclusive prefix
        s.x = fmaf(a.x, s.x, v.x);
        s.y = fmaf(a.y, s.y, v.y);
        s.z = fmaf(a.z, s.z, v.z);
        s.w = fmaf(a.w, s.w, v.w);
    }
}

// ---------------- scan phase 3: rescan + highway gate -----------------
// 4 channels/thread. hin32/hin16: exactly one non-null; same for hout.
__global__ __launch_bounds__(256) void scan_phase3(
    const _Float16* __restrict__ Z, const float* __restrict__ cS,
    const float* __restrict__ hin32, const _Float16* __restrict__ hin16,
    float* __restrict__ hout32, _Float16* __restrict__ hout16)
{
    int ch = threadIdx.x * 4;                  // gridDim.x == 1
    int c  = blockIdx.y;
    int b  = blockIdx.z;
    float s[4];
    {
        float4 s4 = *(const float4*)&cS[((size_t)b * NC + c) * Hd + ch];
        s[0] = s4.x; s[1] = s4.y; s[2] = s4.z; s[3] = s4.w;
    }
    const _Float16* zp = Z + ((size_t)(b * Td + c * CL)) * N3 + ch;
    size_t ho = ((size_t)(b * Td + c * CL)) * Hd + ch;
#pragma unroll 2
    for (int t = 0; t < CL; ++t) {
        half4v h4 = *(const half4v*)(zp);
        half4v g4 = *(const half4v*)(zp + Hd);
        half4v p4 = *(const half4v*)(zp + 2 * Hd);
        float hi[4];
        if (hin32) {
            float4 v = *(const float4*)&hin32[ho];
            hi[0] = v.x; hi[1] = v.y; hi[2] = v.z; hi[3] = v.w;
        } else {
            half4v v = *(const half4v*)&hin16[ho];
#pragma unroll
            for (int i = 0; i < 4; ++i) hi[i] = (float)v[i];
        }
        float o[4];
#pragma unroll
        for (int i = 0; i < 4; ++i) {
            float sg = sigm((float)g4[i]);
            float at = 1.0f - sg;
            s[i] = fmaf(at, s[i], sg * gfun((float)h4[i]));
            float gg = sigm((float)p4[i]);
            o[i] = fmaf(gg, s[i] - hi[i], hi[i]);
        }
        if (hout32) *(float4*)&hout32[ho] = make_float4(o[0], o[1], o[2], o[3]);
        if (hout16) {
            half4v v;
#pragma unroll
            for (int i = 0; i < 4; ++i) v[i] = (_Float16)o[i];
            *(half4v*)&hout16[ho] = v;
        }
        zp += N3; ho += Hd;
    }
}

extern "C" void kernel_launch(void* const* d_in, const int* in_sizes, int n_in,
                              void* d_out, int out_size, void* d_ws, size_t ws_size,
                              hipStream_t stream) {
    const float* h  = (const float*)d_in[0];
    const float* W0 = (const float*)d_in[1];
    const float* W1 = (const float*)d_in[2];
    float* out = (float*)d_out;

    char* ws = (char*)d_ws;
    _Float16* Z    = (_Float16*)ws; ws += (size_t)Md * N3 * 2;     // 192 MiB
    _Float16* Hbf  = (_Float16*)ws; ws += (size_t)Md * Kd * 2;     // 64 MiB
    _Float16* Wt   = (_Float16*)ws; ws += (size_t)N3 * Kd * 2;     // 6 MiB
    float* cA   = (float*)ws; ws += (size_t)Bc * NC * Hd * 4;      // 4 MiB
    float* cB   = (float*)ws; ws += (size_t)Bc * NC * Hd * 4;      // 4 MiB

    // initial h -> fp16
    {
        int n4 = Md * Kd / 4;
        cvt16<<<n4 / 256, 256, 0, stream>>>((const float4*)h, (half4v*)Hbf, n4);
    }

    for (int l = 0; l < 2; ++l) {
        const float* W = l ? W1 : W0;

        wtrans<<<dim3(N3 / 32, Kd / 32), dim3(32, 32), 0, stream>>>(W, Wt);
        gemm_f16_bt_256<<<dim3((Md / BM2) * (N3 / BN2)), 512, 0, stream>>>(Hbf, Wt, Z);
        scan_phase1<<<dim3(1, NC, Bc), 256, 0, stream>>>(Z, cA, cB);
        scan_phase2<<<(Bc * Hd / 4) / 256, 256, 0, stream>>>(cA, cB);
        if (l == 0) {
            scan_phase3<<<dim3(1, NC, Bc), 256, 0, stream>>>(
                Z, cB, h, nullptr, nullptr, Hbf);
        } else {
            scan_phase3<<<dim3(1, NC, Bc), 256, 0, stream>>>(
                Z, cB, nullptr, Hbf, out, nullptr);
        }
    }
}

// Round 6
// 906.112 us; speedup vs baseline: 1.1901x; 1.0178x over previous
//
#include <hip/hip_runtime.h>

#define Bc 8
#define Td 4096
#define Hd 1024
#define N3 3072
#define Md (Bc*Td)      // 32768
#define Kd Hd           // 1024

#define NC 128          // chunks along T
#define CL (Td/NC)      // 32 steps per chunk

// 256^2 deep-pipelined GEMM geometry
#define BM2 256
#define BN2 256
#define BK2 64
#define NT (Kd/BK2)     // 16 K-tiles
#define NSEG (4*NT)     // 64 staging segments

typedef _Float16 half8 __attribute__((ext_vector_type(8)));
typedef _Float16 half4v __attribute__((ext_vector_type(4)));
typedef float floatx4 __attribute__((ext_vector_type(4)));

typedef __attribute__((address_space(3))) unsigned int lds_u32;
typedef __attribute__((address_space(1))) const unsigned int glob_u32;

__device__ __forceinline__ void async_lds16(const void* g, void* l) {
    __builtin_amdgcn_global_load_lds((glob_u32*)g, (lds_u32*)l, 16, 0, 0);
}

// sigmoid, single exp+rcp, no overflow
__device__ __forceinline__ float sigm(float x) {
    return 1.0f / (1.0f + __expf(-x));
}
// g(x) = x>=0 ? x+0.5 : sigmoid(x); exp(-|x|) never overflows
__device__ __forceinline__ float gfun(float x) {
    float e = __expf(-fabsf(x));
    return (x >= 0.0f) ? (x + 0.5f) : e / (1.0f + e);
}

// ---------------- fp32 -> fp16 convert (vectorized x4) ----------------
__global__ void cvt16(const float4* __restrict__ x, half4v* __restrict__ y, int n4) {
    int i = blockIdx.x * blockDim.x + threadIdx.x;
    if (i < n4) {
        float4 v = x[i];
        half4v o;
        o[0] = (_Float16)v.x; o[1] = (_Float16)v.y;
        o[2] = (_Float16)v.z; o[3] = (_Float16)v.w;
        y[i] = o;
    }
}

// ---------------- W [K,N] fp32 -> Wt [N,K] fp16 (LDS-tiled transpose) --
__global__ void wtrans(const float* __restrict__ W, _Float16* __restrict__ Wt) {
    __shared__ float t[32][33];
    int n0 = blockIdx.x * 32, k0 = blockIdx.y * 32;
    int tx = threadIdx.x, ty = threadIdx.y;
    t[ty][tx] = W[(size_t)(k0 + ty) * N3 + n0 + tx];
    __syncthreads();
    Wt[(size_t)(n0 + ty) * Kd + k0 + tx] = (_Float16)t[tx][ty];
}

// ---------------- GEMM: C[M,N] = A[M,K] * Bt[N,K]^T, fp16 in, fp16 out -
// 256x256 tile, BK=64, 8 waves (2Mx4N), 128 KiB LDS as 8 slots of 16 KiB
// ([sel][slot]: 0=Alo,1=Blo,2=Bhi,3=Ahi; 128 rows x 64 cols each).
// Fine interleave: each of the 4 compute phases per K-tile stages ONE
// half-tile segment (2 global_load_lds/thread), prefetch distance 6
// segments; counted s_waitcnt vmcnt(4) once per tile (never 0 steady).
//
// R5 passed (217us, MfmaUtil 41%, VALUBusy 20%). R6 changes (perf only,
// schedule semantics identical):
//  - full #pragma unroll of the 16-tile K-loop: sel/seg/guards fold to
//    compile-time; ds_read addrs fold to base+imm.
//  - staging global pointers hoisted to 8 per-thread registers (gA[4],
//    gB[4]); per-load cost is one folded +kt*64. Targets the measured
//    VALUBusy 20% (~1090 cyc/tile of re-derived address math serialized
//    in the ds-windows between barriers).
//  - dropped P0-close lgkm drain: slots read at P0 are first overwritten
//    >=2 barriers later (Bhi/Ahi staged P0/P1 target the other buffer);
//    only Blo (last read P1, staged P2) and Alo (last read P2, staged P3)
//    are tight -> keep P1-close and P2-close drains.
//
// WAR ledger: seg s overwrites seg s-8's slot; stage of seg s issues at
// phase s-6, >=1 phase-closing barrier after s-8's last ds_read, with
// reads-complete-before-close guaranteed by rule-18 sched_barrier(0)
// pinning + the P1/P2-close lgkm drains. RAW: per-tile vmcnt(4) leaves
// exactly segs 4kt+8,9 outstanding -> tile kt+1 fully landed; barrier
// makes it block-wide.
//
// Raw asm s_barrier (memory clobber) so no compiler vmcnt(0) drain.
// XOR chunk-swizzle on LDS rows (conflict-free, counters=0).
// XCD-aware block swizzle (nwg=1536 % 8 == 0 -> simple bijective form).
__global__ __launch_bounds__(512, 2) void gemm_f16_bt_256(
    const _Float16* __restrict__ A,   // [M,K]
    const _Float16* __restrict__ Bt,  // [N,K]
    _Float16* __restrict__ C)         // [M,N]
{
    __shared__ _Float16 lds[2][4][128 * 64];   // 131072 B

    const int tid  = threadIdx.x;
    const int wave = tid >> 6;        // 0..7
    const int lane = tid & 63;

    // XCD swizzle: 1536 blocks, 8 XCDs, 192 blocks/XCD chunk.
    const int bid = blockIdx.x;
    const int swz = (bid & 7) * (1536 / 8) + (bid >> 3);
    const int by  = swz / 12;         // M-tile index 0..127
    const int bx  = swz - by * 12;    // N-tile index 0..11
    const int bm  = by * BM2;
    const int bn  = bx * BN2;

    const int wm   = (wave >> 2) * 128;   // 0 or 128
    const int wn   = (wave & 3) * 64;     // 0,64,128,192
    const int quad = lane >> 4;
    const int lr   = lane & 15;
    const int aslot = wm ? 3 : 0;             // this wave's A half-slot
    const int bslot = (wn >= 128) ? 2 : 1;    // this wave's B half-slot
    const int bro   = wn & 127;               // local row base in B slot

    floatx4 acc[8][4];
#pragma unroll
    for (int i = 0; i < 8; ++i)
#pragma unroll
        for (int j = 0; j < 4; ++j) { floatx4 z = {0.f,0.f,0.f,0.f}; acc[i][j] = z; }

    // ---- hoisted staging addresses (loop-invariant per thread) ----
    // lane l stages LDS row (q*64|wave*8)+(l>>3), chunk pos l&7; source
    // chunk = pos ^ (row&7); row&7 == l>>3 for all segs (wave*8, 64, 128
    // are 0 mod 8), so kc is one value per thread.
    const int rl0 = wave * 8 + (lane >> 3);          // slot-local row, r=0
    const int kc  = (((lane & 7) ^ (lane >> 3)) << 3);
    const _Float16* gA[4];
    const _Float16* gB[4];
#pragma unroll
    for (int q = 0; q < 4; ++q) {
        gA[q] = A  + (size_t)(bm + q * 64 + rl0) * Kd + kc;
        gB[q] = Bt + (size_t)(bn + q * 64 + rl0) * Kd + kc;
    }

    // stage one 128x64 segment: seg = 4*ktile + b, b: 0=Blo 1=Alo 2=Bhi 3=Ahi
    // (seg is compile-time after full unroll -> all selects fold)
    auto stage_seg = [&](int seg) {
        const int tt    = seg >> 2;
        const int b     = seg & 3;
        const int sel   = tt & 1;
        const bool isA  = (b & 1);
        const int qb    = (b >= 2) ? 2 : 0;
        const int slot  = (b < 2) ? (1 - b) : b;
#pragma unroll
        for (int r = 0; r < 2; ++r) {
            const _Float16* g = (isA ? gA[qb + r] : gB[qb + r]) + tt * BK2;
            char* l = (char*)&lds[sel][slot][0] + (r * 64 + wave * 8) * 128;
            async_lds16(g, l);
        }
    };

    // fragment reads (XOR-deswizzled); rows are slot-local (0..127)
    auto dsA = [&](int sel, int ih, half8 (&af)[4][2]) {
#pragma unroll
        for (int i = 0; i < 4; ++i) {
            int row = (ih * 4 + i) * 16 + lr;
#pragma unroll
            for (int ks = 0; ks < 2; ++ks) {
                int ck = ((ks * 4 + quad) ^ (row & 7)) << 3;
                af[i][ks] = *(const half8*)&lds[sel][aslot][row * 64 + ck];
            }
        }
    };
    auto dsB = [&](int sel, int jh, half8 (&bf)[2][2]) {
#pragma unroll
        for (int j = 0; j < 2; ++j) {
            int row = bro + (jh * 2 + j) * 16 + lr;
#pragma unroll
            for (int ks = 0; ks < 2; ++ks) {
                int ck = ((ks * 4 + quad) ^ (row & 7)) << 3;
                bf[j][ks] = *(const half8*)&lds[sel][bslot][row * 64 + ck];
            }
        }
    };
    // sched_barrier(0) fences pin the MFMA cluster (and its lgkmcnt wait)
    // strictly between the enclosing s_barriers (rule #18).
    auto mmac = [&](int ih, int jh, half8 (&af)[4][2], half8 (&bf)[2][2]) {
        __builtin_amdgcn_sched_barrier(0);
        __builtin_amdgcn_s_setprio(1);
#pragma unroll
        for (int i = 0; i < 4; ++i)
#pragma unroll
            for (int j = 0; j < 2; ++j)
#pragma unroll
                for (int ks = 0; ks < 2; ++ks)
                    acc[ih * 4 + i][jh * 2 + j] =
                        __builtin_amdgcn_mfma_f32_16x16x32_f16(
                            af[i][ks], bf[j][ks],
                            acc[ih * 4 + i][jh * 2 + j], 0, 0, 0);
        __builtin_amdgcn_s_setprio(0);
        __builtin_amdgcn_sched_barrier(0);
    };

    half8 af[4][2], bf0[2][2], bf1[2][2];

    // ---- prologue: segments 0..5 (tile0 complete + tile1 Blo,Alo) ----
#pragma unroll
    for (int s = 0; s < 6; ++s) stage_seg(s);
    asm volatile("s_waitcnt vmcnt(4)" ::: "memory");   // tile0 landed, 2 segs in flight
    asm volatile("s_barrier" ::: "memory");

#pragma unroll
    for (int kt = 0; kt < NT; ++kt) {
        const int sel = kt & 1;
        const int p = kt * 4;
        // P0: quadrant (0,0); stage seg p+6
        dsA(sel, 0, af); dsB(sel, 0, bf0);
        if (p + 6 < NSEG) stage_seg(p + 6);
        asm volatile("s_barrier" ::: "memory");
        mmac(0, 0, af, bf0);
        asm volatile("s_barrier" ::: "memory");
        // P1: quadrant (0,1); stage seg p+7
        dsB(sel, 1, bf1);
        if (p + 7 < NSEG) stage_seg(p + 7);
        asm volatile("s_barrier" ::: "memory");
        mmac(0, 1, af, bf1);
        asm volatile("s_waitcnt lgkmcnt(0)" ::: "memory");  // Blo reads drained
        asm volatile("s_barrier" ::: "memory");
        // P2: quadrant (1,0); stage seg p+8
        dsA(sel, 1, af);
        if (p + 8 < NSEG) stage_seg(p + 8);
        asm volatile("s_barrier" ::: "memory");
        mmac(1, 0, af, bf0);
        asm volatile("s_waitcnt lgkmcnt(0)" ::: "memory");  // Alo reads drained
        asm volatile("s_barrier" ::: "memory");
        // P3: quadrant (1,1), register-only; stage seg p+9
        if (p + 9 < NSEG) stage_seg(p + 9);
        mmac(1, 1, af, bf1);
        if (kt < NT - 2) {
            asm volatile("s_waitcnt vmcnt(4)" ::: "memory");  // next tile landed
            asm volatile("s_barrier" ::: "memory");
        } else if (kt == NT - 2) {
            asm volatile("s_waitcnt vmcnt(0)" ::: "memory");  // last tile landed
            asm volatile("s_barrier" ::: "memory");
        }
    }

    // epilogue: C/D layout col = lane&15, row = quad*4 + reg  [m89-verified]
#pragma unroll
    for (int i = 0; i < 8; ++i) {
#pragma unroll
        for (int j = 0; j < 4; ++j) {
            int row0 = bm + wm + i * 16 + quad * 4;
            int col  = bn + wn + j * 16 + lr;
#pragma unroll
            for (int r = 0; r < 4; ++r)
                C[(size_t)(row0 + r) * N3 + col] = (_Float16)acc[i][j][r];
        }
    }
}

// ---------------- scan phase 1: per-chunk (A, B) composition ----------
// 4 channels/thread: half4 (8B) loads, 4 independent chains for ILP.
__global__ __launch_bounds__(256) void scan_phase1(
    const _Float16* __restrict__ Z, float* __restrict__ cA, float* __restrict__ cB)
{
    int ch = threadIdx.x * 4;                  // gridDim.x == 1, covers H=1024
    int c  = blockIdx.y;
    int b  = blockIdx.z;
    const _Float16* zp = Z + ((size_t)(b * Td + c * CL)) * N3 + ch;
    float Ap[4] = {1.f, 1.f, 1.f, 1.f};
    float Bv[4] = {0.f, 0.f, 0.f, 0.f};
#pragma unroll 4
    for (int t = 0; t < CL; ++t) {
        half4v h4 = *(const half4v*)(zp);
        half4v g4 = *(const half4v*)(zp + Hd);
#pragma unroll
        for (int i = 0; i < 4; ++i) {
            float sg = sigm((float)g4[i]);
            float at = 1.0f - sg;
            float bt = sg * gfun((float)h4[i]);
            Ap[i] *= at;
            Bv[i] = fmaf(at, Bv[i], bt);
        }
        zp += N3;
    }
    size_t o = ((size_t)b * NC + c) * Hd + ch;
    *(float4*)&cA[o] = make_float4(Ap[0], Ap[1], Ap[2], Ap[3]);
    *(float4*)&cB[o] = make_float4(Bv[0], Bv[1], Bv[2], Bv[3]);
}

// ---------------- scan phase 2: Kogge-Stone prefix over chunks --------
// R6: replaced the 2048-thread serial-latency kernel (128 dependent HBM
// iterations on 8 blocks, ~25-45us/layer) with a parallel scan: block per
// (channel-group-of-4, b), thread per chunk; 7 LDS rounds. Exclusive
// prefix written in-place into cB (same semantics as before).
// Composition: applying older (Ao,Vo) then current (a,v):
//   v' = a*Vo + v ; a' = a*Ao.
__global__ __launch_bounds__(128) void scan_phase2(
    const float* __restrict__ cA, float* __restrict__ cB)
{
    const int c   = threadIdx.x;      // chunk 0..127
    const int chg = blockIdx.x;       // 0..255 (channel group of 4)
    const int b   = blockIdx.y;
    const size_t o = ((size_t)b * NC + c) * Hd + chg * 4;
    float4 a4 = *(const float4*)&cA[o];
    float4 v4 = *(const float4*)&cB[o];
    float a[4] = {a4.x, a4.y, a4.z, a4.w};
    float v[4] = {v4.x, v4.y, v4.z, v4.w};
    __shared__ float sA[4][NC], sV[4][NC];
#pragma unroll
    for (int d = 1; d < NC; d <<= 1) {
#pragma unroll
        for (int i = 0; i < 4; ++i) { sA[i][c] = a[i]; sV[i][c] = v[i]; }
        __syncthreads();
        if (c >= d) {
#pragma unroll
            for (int i = 0; i < 4; ++i) {
                float ao = sA[i][c - d], vo = sV[i][c - d];
                v[i] = fmaf(a[i], vo, v[i]);   // v += a*Vo (old a)
                a[i] *= ao;
            }
        }
        __syncthreads();
    }
    // v[] is now the inclusive prefix; shift right for exclusive.
#pragma unroll
    for (int i = 0; i < 4; ++i) sV[i][c] = v[i];
    __syncthreads();
    float4 out;
    if (c == 0) out = make_float4(0.f, 0.f, 0.f, 0.f);
    else        out = make_float4(sV[0][c-1], sV[1][c-1], sV[2][c-1], sV[3][c-1]);
    *(float4*)&cB[o] = out;
}

// ---------------- scan phase 3: rescan + highway gate -----------------
// 4 channels/thread. hin32/hin16: exactly one non-null; same for hout.
__global__ __launch_bounds__(256) void scan_phase3(
    const _Float16* __restrict__ Z, const float* __restrict__ cS,
    const float* __restrict__ hin32, const _Float16* __restrict__ hin16,
    float* __restrict__ hout32, _Float16* __restrict__ hout16)
{
    int ch = threadIdx.x * 4;                  // gridDim.x == 1
    int c  = blockIdx.y;
    int b  = blockIdx.z;
    float s[4];
    {
        float4 s4 = *(const float4*)&cS[((size_t)b * NC + c) * Hd + ch];
        s[0] = s4.x; s[1] = s4.y; s[2] = s4.z; s[3] = s4.w;
    }
    const _Float16* zp = Z + ((size_t)(b * Td + c * CL)) * N3 + ch;
    size_t ho = ((size_t)(b * Td + c * CL)) * Hd + ch;
#pragma unroll 2
    for (int t = 0; t < CL; ++t) {
        half4v h4 = *(const half4v*)(zp);
        half4v g4 = *(const half4v*)(zp + Hd);
        half4v p4 = *(const half4v*)(zp + 2 * Hd);
        float hi[4];
        if (hin32) {
            float4 v = *(const float4*)&hin32[ho];
            hi[0] = v.x; hi[1] = v.y; hi[2] = v.z; hi[3] = v.w;
        } else {
            half4v v = *(const half4v*)&hin16[ho];
#pragma unroll
            for (int i = 0; i < 4; ++i) hi[i] = (float)v[i];
        }
        float o[4];
#pragma unroll
        for (int i = 0; i < 4; ++i) {
            float sg = sigm((float)g4[i]);
            float at = 1.0f - sg;
            s[i] = fmaf(at, s[i], sg * gfun((float)h4[i]));
            float gg = sigm((float)p4[i]);
            o[i] = fmaf(gg, s[i] - hi[i], hi[i]);
        }
        if (hout32) *(float4*)&hout32[ho] = make_float4(o[0], o[1], o[2], o[3]);
        if (hout16) {
            half4v v;
#pragma unroll
            for (int i = 0; i < 4; ++i) v[i] = (_Float16)o[i];
            *(half4v*)&hout16[ho] = v;
        }
        zp += N3; ho += Hd;
    }
}

extern "C" void kernel_launch(void* const* d_in, const int* in_sizes, int n_in,
                              void* d_out, int out_size, void* d_ws, size_t ws_size,
                              hipStream_t stream) {
    const float* h  = (const float*)d_in[0];
    const float* W0 = (const float*)d_in[1];
    const float* W1 = (const float*)d_in[2];
    float* out = (float*)d_out;

    char* ws = (char*)d_ws;
    _Float16* Z    = (_Float16*)ws; ws += (size_t)Md * N3 * 2;     // 192 MiB
    _Float16* Hbf  = (_Float16*)ws; ws += (size_t)Md * Kd * 2;     // 64 MiB
    _Float16* Wt   = (_Float16*)ws; ws += (size_t)N3 * Kd * 2;     // 6 MiB
    float* cA   = (float*)ws; ws += (size_t)Bc * NC * Hd * 4;      // 4 MiB
    float* cB   = (float*)ws; ws += (size_t)Bc * NC * Hd * 4;      // 4 MiB

    // initial h -> fp16
    {
        int n4 = Md * Kd / 4;
        cvt16<<<n4 / 256, 256, 0, stream>>>((const float4*)h, (half4v*)Hbf, n4);
    }

    for (int l = 0; l < 2; ++l) {
        const float* W = l ? W1 : W0;

        wtrans<<<dim3(N3 / 32, Kd / 32), dim3(32, 32), 0, stream>>>(W, Wt);
        gemm_f16_bt_256<<<dim3((Md / BM2) * (N3 / BN2)), 512, 0, stream>>>(Hbf, Wt, Z);
        scan_phase1<<<dim3(1, NC, Bc), 256, 0, stream>>>(Z, cA, cB);
        scan_phase2<<<dim3(Hd / 4, Bc), 128, 0, stream>>>(cA, cB);
        if (l == 0) {
            scan_phase3<<<dim3(1, NC, Bc), 256, 0, stream>>>(
                Z, cB, h, nullptr, nullptr, Hbf);
        } else {
            scan_phase3<<<dim3(1, NC, Bc), 256, 0, stream>>>(
                Z, cB, nullptr, Hbf, out, nullptr);
        }
    }
}

// Round 7
// 894.985 us; speedup vs baseline: 1.2049x; 1.0124x over previous
//
#include <hip/hip_runtime.h>

#define Bc 8
#define Td 4096
#define Hd 1024
#define N3 3072
#define Md (Bc*Td)      // 32768
#define Kd Hd           // 1024

#define NC 128          // chunks along T
#define CL (Td/NC)      // 32 steps per chunk

// 256^2 deep-pipelined GEMM geometry
#define BM2 256
#define BN2 256
#define BK2 64
#define NT (Kd/BK2)     // 16 K-tiles
#define NSEG (4*NT)     // 64 staging segments

typedef _Float16 half8 __attribute__((ext_vector_type(8)));
typedef _Float16 half4v __attribute__((ext_vector_type(4)));
typedef float floatx4 __attribute__((ext_vector_type(4)));

typedef __attribute__((address_space(3))) unsigned int lds_u32;
typedef __attribute__((address_space(1))) const unsigned int glob_u32;

__device__ __forceinline__ void async_lds16(const void* g, void* l) {
    __builtin_amdgcn_global_load_lds((glob_u32*)g, (lds_u32*)l, 16, 0, 0);
}

// sigmoid, single exp+rcp, no overflow
__device__ __forceinline__ float sigm(float x) {
    return 1.0f / (1.0f + __expf(-x));
}
// g(x) = x>=0 ? x+0.5 : sigmoid(x); exp(-|x|) never overflows
__device__ __forceinline__ float gfun(float x) {
    float e = __expf(-fabsf(x));
    return (x >= 0.0f) ? (x + 0.5f) : e / (1.0f + e);
}

// ---------------- fp32 -> fp16 convert (vectorized x4) ----------------
__global__ void cvt16(const float4* __restrict__ x, half4v* __restrict__ y, int n4) {
    int i = blockIdx.x * blockDim.x + threadIdx.x;
    if (i < n4) {
        float4 v = x[i];
        half4v o;
        o[0] = (_Float16)v.x; o[1] = (_Float16)v.y;
        o[2] = (_Float16)v.z; o[3] = (_Float16)v.w;
        y[i] = o;
    }
}

// ---------------- W [K,N] fp32 -> Wt [N,K] fp16 (LDS-tiled transpose) --
__global__ void wtrans(const float* __restrict__ W, _Float16* __restrict__ Wt) {
    __shared__ float t[32][33];
    int n0 = blockIdx.x * 32, k0 = blockIdx.y * 32;
    int tx = threadIdx.x, ty = threadIdx.y;
    t[ty][tx] = W[(size_t)(k0 + ty) * N3 + n0 + tx];
    __syncthreads();
    Wt[(size_t)(n0 + ty) * Kd + k0 + tx] = (_Float16)t[tx][ty];
}

// ---------------- GEMM: C[M,N] = A[M,K] * Bt[N,K]^T, fp16 in, fp16 out -
// 256x256 tile, BK=64, 8 waves (2Mx4N), 128 KiB LDS as 8 slots of 16 KiB
// ([sel][slot]: 0=Alo,1=Blo,2=Bhi,3=Ahi; 128 rows x 64 cols each).
// Fine interleave: each of the 4 compute phases per K-tile stages ONE
// half-tile segment (2 global_load_lds/thread), prefetch distance 6
// segments; counted s_waitcnt vmcnt(4) once per tile (never 0 steady;
// vmcnt counts LOADS, 2/seg -> 4 = last 2 segs in flight).
//
// R7: REMOVED the sched_barrier(0) fences around MFMA clusters. R6
// counters (MfmaUtil 45%, 5078 cyc/tile vs m201's 3300) showed the pins
// forbid the m201-style overlap of phase-k MFMA drain with phase-k+1
// ds_read/stage issue. They were added in R3 for a phantom race (R4
// post-mortem: the failure was the deterministic `bro` bug). WAR
// correctness needs only "ds_reads retire before the phase-CLOSING
// barrier", which the explicit lgkmcnt(0) drains guarantee alone:
//   Blo[sel]: last read P1 ds-window; overwritten by seg p+8 at P2;
//             P1-close lgkm drain covers (2 barriers between).
//   Alo[sel]: last read P2; overwritten by seg p+9 at P3; P2-close
//             drain covers.
//   Bhi/Ahi: overwritten next tile (>=3 barriers margin).
// MFMAs sinking past barriers is harmless: they consume registers, and
// compiler-tracked ds_read->MFMA register deps are always honored
// (rule 18 applies to inline-asm ds_reads only).
// RAW: tile-end vmcnt(4) -> next tile's 4 segs landed; barrier makes it
// block-wide.
//
// Raw asm s_barrier (memory clobber) so no compiler vmcnt(0) drain.
// XOR chunk-swizzle on LDS rows (conflict-free, counters=0).
// XCD-aware block swizzle (nwg=1536 % 8 == 0 -> simple bijective form).
__global__ __launch_bounds__(512, 2) void gemm_f16_bt_256(
    const _Float16* __restrict__ A,   // [M,K]
    const _Float16* __restrict__ Bt,  // [N,K]
    _Float16* __restrict__ C)         // [M,N]
{
    __shared__ _Float16 lds[2][4][128 * 64];   // 131072 B

    const int tid  = threadIdx.x;
    const int wave = tid >> 6;        // 0..7
    const int lane = tid & 63;

    // XCD swizzle: 1536 blocks, 8 XCDs, 192 blocks/XCD chunk.
    const int bid = blockIdx.x;
    const int swz = (bid & 7) * (1536 / 8) + (bid >> 3);
    const int by  = swz / 12;         // M-tile index 0..127
    const int bx  = swz - by * 12;    // N-tile index 0..11
    const int bm  = by * BM2;
    const int bn  = bx * BN2;

    const int wm   = (wave >> 2) * 128;   // 0 or 128
    const int wn   = (wave & 3) * 64;     // 0,64,128,192
    const int quad = lane >> 4;
    const int lr   = lane & 15;
    const int aslot = wm ? 3 : 0;             // this wave's A half-slot
    const int bslot = (wn >= 128) ? 2 : 1;    // this wave's B half-slot
    const int bro   = wn & 127;               // local row base in B slot

    floatx4 acc[8][4];
#pragma unroll
    for (int i = 0; i < 8; ++i)
#pragma unroll
        for (int j = 0; j < 4; ++j) { floatx4 z = {0.f,0.f,0.f,0.f}; acc[i][j] = z; }

    // ---- hoisted staging addresses (loop-invariant per thread) ----
    const int rl0 = wave * 8 + (lane >> 3);          // slot-local row, r=0
    const int kc  = (((lane & 7) ^ (lane >> 3)) << 3);
    const _Float16* gA[4];
    const _Float16* gB[4];
#pragma unroll
    for (int q = 0; q < 4; ++q) {
        gA[q] = A  + (size_t)(bm + q * 64 + rl0) * Kd + kc;
        gB[q] = Bt + (size_t)(bn + q * 64 + rl0) * Kd + kc;
    }

    // stage one 128x64 segment: seg = 4*ktile + b, b: 0=Blo 1=Alo 2=Bhi 3=Ahi
    // (seg is compile-time after full unroll -> all selects fold)
    auto stage_seg = [&](int seg) {
        const int tt    = seg >> 2;
        const int b     = seg & 3;
        const int sel   = tt & 1;
        const bool isA  = (b & 1);
        const int qb    = (b >= 2) ? 2 : 0;
        const int slot  = (b < 2) ? (1 - b) : b;
#pragma unroll
        for (int r = 0; r < 2; ++r) {
            const _Float16* g = (isA ? gA[qb + r] : gB[qb + r]) + tt * BK2;
            char* l = (char*)&lds[sel][slot][0] + (r * 64 + wave * 8) * 128;
            async_lds16(g, l);
        }
    };

    // fragment reads (XOR-deswizzled); rows are slot-local (0..127)
    auto dsA = [&](int sel, int ih, half8 (&af)[4][2]) {
#pragma unroll
        for (int i = 0; i < 4; ++i) {
            int row = (ih * 4 + i) * 16 + lr;
#pragma unroll
            for (int ks = 0; ks < 2; ++ks) {
                int ck = ((ks * 4 + quad) ^ (row & 7)) << 3;
                af[i][ks] = *(const half8*)&lds[sel][aslot][row * 64 + ck];
            }
        }
    };
    auto dsB = [&](int sel, int jh, half8 (&bf)[2][2]) {
#pragma unroll
        for (int j = 0; j < 2; ++j) {
            int row = bro + (jh * 2 + j) * 16 + lr;
#pragma unroll
            for (int ks = 0; ks < 2; ++ks) {
                int ck = ((ks * 4 + quad) ^ (row & 7)) << 3;
                bf[j][ks] = *(const half8*)&lds[sel][bslot][row * 64 + ck];
            }
        }
    };
    auto mmac = [&](int ih, int jh, half8 (&af)[4][2], half8 (&bf)[2][2]) {
        __builtin_amdgcn_s_setprio(1);
#pragma unroll
        for (int i = 0; i < 4; ++i)
#pragma unroll
            for (int j = 0; j < 2; ++j)
#pragma unroll
                for (int ks = 0; ks < 2; ++ks)
                    acc[ih * 4 + i][jh * 2 + j] =
                        __builtin_amdgcn_mfma_f32_16x16x32_f16(
                            af[i][ks], bf[j][ks],
                            acc[ih * 4 + i][jh * 2 + j], 0, 0, 0);
        __builtin_amdgcn_s_setprio(0);
    };

    half8 af[4][2], bf0[2][2], bf1[2][2];

    // ---- prologue: segments 0..5 (tile0 complete + tile1 Blo,Alo) ----
#pragma unroll
    for (int s = 0; s < 6; ++s) stage_seg(s);
    asm volatile("s_waitcnt vmcnt(4)" ::: "memory");   // tile0 landed, 2 segs in flight
    asm volatile("s_barrier" ::: "memory");

#pragma unroll
    for (int kt = 0; kt < NT; ++kt) {
        const int sel = kt & 1;
        const int p = kt * 4;
        // P0: quadrant (0,0); stage seg p+6
        dsA(sel, 0, af); dsB(sel, 0, bf0);
        if (p + 6 < NSEG) stage_seg(p + 6);
        asm volatile("s_barrier" ::: "memory");
        mmac(0, 0, af, bf0);
        asm volatile("s_barrier" ::: "memory");
        // P1: quadrant (0,1); stage seg p+7
        dsB(sel, 1, bf1);
        if (p + 7 < NSEG) stage_seg(p + 7);
        asm volatile("s_barrier" ::: "memory");
        mmac(0, 1, af, bf1);
        asm volatile("s_waitcnt lgkmcnt(0)" ::: "memory");  // Blo reads drained
        asm volatile("s_barrier" ::: "memory");
        // P2: quadrant (1,0); stage seg p+8
        dsA(sel, 1, af);
        if (p + 8 < NSEG) stage_seg(p + 8);
        asm volatile("s_barrier" ::: "memory");
        mmac(1, 0, af, bf0);
        asm volatile("s_waitcnt lgkmcnt(0)" ::: "memory");  // Alo reads drained
        asm volatile("s_barrier" ::: "memory");
        // P3: quadrant (1,1), register-only; stage seg p+9
        if (p + 9 < NSEG) stage_seg(p + 9);
        mmac(1, 1, af, bf1);
        if (kt < NT - 2) {
            asm volatile("s_waitcnt vmcnt(4)" ::: "memory");  // next tile landed
            asm volatile("s_barrier" ::: "memory");
        } else if (kt == NT - 2) {
            asm volatile("s_waitcnt vmcnt(0)" ::: "memory");  // last tile landed
            asm volatile("s_barrier" ::: "memory");
        }
    }

    // epilogue: C/D layout col = lane&15, row = quad*4 + reg  [m89-verified]
#pragma unroll
    for (int i = 0; i < 8; ++i) {
#pragma unroll
        for (int j = 0; j < 4; ++j) {
            int row0 = bm + wm + i * 16 + quad * 4;
            int col  = bn + wn + j * 16 + lr;
#pragma unroll
            for (int r = 0; r < 4; ++r)
                C[(size_t)(row0 + r) * N3 + col] = (_Float16)acc[i][j][r];
        }
    }
}

// ---------------- scan phase 1: per-chunk (A, B) composition ----------
// 4 channels/thread: half4 (8B) loads, 4 independent chains for ILP.
__global__ __launch_bounds__(256) void scan_phase1(
    const _Float16* __restrict__ Z, float* __restrict__ cA, float* __restrict__ cB)
{
    int ch = threadIdx.x * 4;                  // gridDim.x == 1, covers H=1024
    int c  = blockIdx.y;
    int b  = blockIdx.z;
    const _Float16* zp = Z + ((size_t)(b * Td + c * CL)) * N3 + ch;
    float Ap[4] = {1.f, 1.f, 1.f, 1.f};
    float Bv[4] = {0.f, 0.f, 0.f, 0.f};
#pragma unroll 4
    for (int t = 0; t < CL; ++t) {
        half4v h4 = *(const half4v*)(zp);
        half4v g4 = *(const half4v*)(zp + Hd);
#pragma unroll
        for (int i = 0; i < 4; ++i) {
            float sg = sigm((float)g4[i]);
            float at = 1.0f - sg;
            float bt = sg * gfun((float)h4[i]);
            Ap[i] *= at;
            Bv[i] = fmaf(at, Bv[i], bt);
        }
        zp += N3;
    }
    size_t o = ((size_t)b * NC + c) * Hd + ch;
    *(float4*)&cA[o] = make_float4(Ap[0], Ap[1], Ap[2], Ap[3]);
    *(float4*)&cB[o] = make_float4(Bv[0], Bv[1], Bv[2], Bv[3]);
}

// ---------------- scan phase 2: Kogge-Stone prefix over chunks --------
// Block per (channel-group-of-4, b), thread per chunk; 7 LDS rounds.
// Exclusive prefix written in-place into cB.
__global__ __launch_bounds__(128) void scan_phase2(
    const float* __restrict__ cA, float* __restrict__ cB)
{
    const int c   = threadIdx.x;      // chunk 0..127
    const int chg = blockIdx.x;       // 0..255 (channel group of 4)
    const int b   = blockIdx.y;
    const size_t o = ((size_t)b * NC + c) * Hd + chg * 4;
    float4 a4 = *(const float4*)&cA[o];
    float4 v4 = *(const float4*)&cB[o];
    float a[4] = {a4.x, a4.y, a4.z, a4.w};
    float v[4] = {v4.x, v4.y, v4.z, v4.w};
    __shared__ float sA[4][NC], sV[4][NC];
#pragma unroll
    for (int d = 1; d < NC; d <<= 1) {
#pragma unroll
        for (int i = 0; i < 4; ++i) { sA[i][c] = a[i]; sV[i][c] = v[i]; }
        __syncthreads();
        if (c >= d) {
#pragma unroll
            for (int i = 0; i < 4; ++i) {
                float ao = sA[i][c - d], vo = sV[i][c - d];
                v[i] = fmaf(a[i], vo, v[i]);   // v += a*Vo (old a)
                a[i] *= ao;
            }
        }
        __syncthreads();
    }
    // v[] is now the inclusive prefix; shift right for exclusive.
#pragma unroll
    for (int i = 0; i < 4; ++i) sV[i][c] = v[i];
    __syncthreads();
    float4 out;
    if (c == 0) out = make_float4(0.f, 0.f, 0.f, 0.f);
    else        out = make_float4(sV[0][c-1], sV[1][c-1], sV[2][c-1], sV[3][c-1]);
    *(float4*)&cB[o] = out;
}

// ---------------- scan phase 3: rescan + highway gate -----------------
// 4 channels/thread. R7: fp16 h everywhere (Hbf holds cvt16(h) at l=0;
// highway-term rounding err ~1e-3 << threshold 0.076). hout32/hout16:
// exactly one non-null.
__global__ __launch_bounds__(256) void scan_phase3(
    const _Float16* __restrict__ Z, const float* __restrict__ cS,
    const _Float16* __restrict__ hin16,
    float* __restrict__ hout32, _Float16* __restrict__ hout16)
{
    int ch = threadIdx.x * 4;                  // gridDim.x == 1
    int c  = blockIdx.y;
    int b  = blockIdx.z;
    float s[4];
    {
        float4 s4 = *(const float4*)&cS[((size_t)b * NC + c) * Hd + ch];
        s[0] = s4.x; s[1] = s4.y; s[2] = s4.z; s[3] = s4.w;
    }
    const _Float16* zp = Z + ((size_t)(b * Td + c * CL)) * N3 + ch;
    size_t ho = ((size_t)(b * Td + c * CL)) * Hd + ch;
#pragma unroll 2
    for (int t = 0; t < CL; ++t) {
        half4v h4 = *(const half4v*)(zp);
        half4v g4 = *(const half4v*)(zp + Hd);
        half4v p4 = *(const half4v*)(zp + 2 * Hd);
        half4v hv = *(const half4v*)&hin16[ho];
        float o[4];
#pragma unroll
        for (int i = 0; i < 4; ++i) {
            float hi = (float)hv[i];
            float sg = sigm((float)g4[i]);
            float at = 1.0f - sg;
            s[i] = fmaf(at, s[i], sg * gfun((float)h4[i]));
            float gg = sigm((float)p4[i]);
            o[i] = fmaf(gg, s[i] - hi, hi);
        }
        if (hout32) *(float4*)&hout32[ho] = make_float4(o[0], o[1], o[2], o[3]);
        if (hout16) {
            half4v v;
#pragma unroll
            for (int i = 0; i < 4; ++i) v[i] = (_Float16)o[i];
            *(half4v*)&hout16[ho] = v;
        }
        zp += N3; ho += Hd;
    }
}

extern "C" void kernel_launch(void* const* d_in, const int* in_sizes, int n_in,
                              void* d_out, int out_size, void* d_ws, size_t ws_size,
                              hipStream_t stream) {
    const float* h  = (const float*)d_in[0];
    const float* W0 = (const float*)d_in[1];
    const float* W1 = (const float*)d_in[2];
    float* out = (float*)d_out;

    char* ws = (char*)d_ws;
    _Float16* Z    = (_Float16*)ws; ws += (size_t)Md * N3 * 2;     // 192 MiB
    _Float16* Hbf  = (_Float16*)ws; ws += (size_t)Md * Kd * 2;     // 64 MiB
    _Float16* Wt   = (_Float16*)ws; ws += (size_t)N3 * Kd * 2;     // 6 MiB
    float* cA   = (float*)ws; ws += (size_t)Bc * NC * Hd * 4;      // 4 MiB
    float* cB   = (float*)ws; ws += (size_t)Bc * NC * Hd * 4;      // 4 MiB

    // initial h -> fp16
    {
        int n4 = Md * Kd / 4;
        cvt16<<<n4 / 256, 256, 0, stream>>>((const float4*)h, (half4v*)Hbf, n4);
    }

    for (int l = 0; l < 2; ++l) {
        const float* W = l ? W1 : W0;

        wtrans<<<dim3(N3 / 32, Kd / 32), dim3(32, 32), 0, stream>>>(W, Wt);
        gemm_f16_bt_256<<<dim3((Md / BM2) * (N3 / BN2)), 512, 0, stream>>>(Hbf, Wt, Z);
        scan_phase1<<<dim3(1, NC, Bc), 256, 0, stream>>>(Z, cA, cB);
        scan_phase2<<<dim3(Hd / 4, Bc), 128, 0, stream>>>(cA, cB);
        if (l == 0) {
            // in-place h update: read Hbf, write Hbf (same thread, same addr)
            scan_phase3<<<dim3(1, NC, Bc), 256, 0, stream>>>(
                Z, cB, Hbf, nullptr, Hbf);
        } else {
            scan_phase3<<<dim3(1, NC, Bc), 256, 0, stream>>>(
                Z, cB, Hbf, out, nullptr);
        }
    }
}